// Round 1
// baseline (10.229 us; speedup 1.0000x reference)
//
#include <hip/hip_runtime.h>

#define W    16      // CHUNK
#define TILE 256     // outputs per block

// out[b,t] = E[t] * sum_{k=0..15} emit[t+k] / S[t+k]
//   E[j] = exp(logits[j])   (E=0 for j<0, j>=T  -- matches -FMAX padding)
//   S[u] = sum_{j=u-15..u} E[j]
//   g[u] = emit[u]/S[u] for u<T else 0          -- matches 0 / FMAX padding
__global__ __launch_bounds__(TILE)
void mocha_chunkwise_kernel(const float* __restrict__ emit,
                            const float* __restrict__ logits,
                            float* __restrict__ out,
                            int T)
{
    const int b   = blockIdx.y;
    const int t0  = blockIdx.x * TILE;
    const int tid = threadIdx.x;

    const float* lrow = logits + (size_t)b * T;
    const float* erow = emit   + (size_t)b * T;
    float*       orow = out    + (size_t)b * T;

    // Es[i] = E[t0 - 15 + i], i in [0, 286)
    __shared__ float Es[TILE + 2 * W - 2 + 2];   // 288 (286 used)
    // Gs[i] = g[t0 + i], i in [0, 271)
    __shared__ float Gs[TILE + W];               // 272 (271 used)

    for (int i = tid; i < TILE + 2 * W - 2; i += TILE) {
        int j = t0 - (W - 1) + i;
        float e = 0.0f;
        if (j >= 0 && j < T) e = __expf(lrow[j]);
        Es[i] = e;
    }
    __syncthreads();

    for (int i = tid; i < TILE + W - 1; i += TILE) {
        int u = t0 + i;
        float s = 0.0f;
        #pragma unroll
        for (int k = 0; k < W; ++k) s += Es[i + k];
        float g = 0.0f;
        if (u < T) g = __fdividef(erow[u], s);   // s >= E[u] > 0 for u < T
        Gs[i] = g;
    }
    __syncthreads();

    const int t = t0 + tid;
    if (t < T) {
        float acc = 0.0f;
        #pragma unroll
        for (int k = 0; k < W; ++k) acc += Gs[tid + k];
        orow[t] = Es[tid + (W - 1)] * acc;
    }
}

extern "C" void kernel_launch(void* const* d_in, const int* in_sizes, int n_in,
                              void* d_out, int out_size, void* d_ws, size_t ws_size,
                              hipStream_t stream)
{
    const float* emit   = (const float*)d_in[0];   // emit_probs     [B,T]
    const float* logits = (const float*)d_in[1];   // softmax_logits [B,T]
    float*       out    = (float*)d_out;           // [B,T] fp32

    const int T = 16384;
    const int B = in_sizes[0] / T;                 // 64

    dim3 grid((T + TILE - 1) / TILE, B);
    dim3 block(TILE);
    mocha_chunkwise_kernel<<<grid, block, 0, stream>>>(emit, logits, out, T);
}